// Round 1
// baseline (2648.300 us; speedup 1.0000x reference)
//
#include <hip/hip_runtime.h>
#include <math.h>

#define T_TOK 1024
#define DIM   2048
#define NE    32
#define I_R   1408
#define I_S   2816

// ---------------- gating ----------------
__global__ void gate_kernel(const float* __restrict__ x,
                            const float* __restrict__ gate_w,
                            const float* __restrict__ gate_b,
                            int* __restrict__ counts,
                            int* __restrict__ toks,
                            float* __restrict__ wts)
{
    const int t   = blockIdx.x;
    const int tid = threadIdx.x;
    __shared__ float xs[DIM];
    __shared__ float sc_s[NE];   // sigmoid scores
    __shared__ float sfc_s[NE];  // scores + bias (for choice)

    for (int i = tid; i < DIM; i += 256) xs[i] = x[(size_t)t * DIM + i];
    __syncthreads();

    const int wave = tid >> 6, lane = tid & 63;
    for (int q = 0; q < 8; ++q) {
        const int e = wave * 8 + q;
        const float* gw = gate_w + (size_t)e * DIM;
        float s = 0.f;
        for (int d = lane; d < DIM; d += 64) s += xs[d] * gw[d];
        for (int off = 32; off >= 1; off >>= 1) s += __shfl_down(s, off, 64);
        if (lane == 0) {
            float logit = s + gate_b[e];          // linear bias
            float sc = 1.f / (1.f + expf(-logit));
            sc_s[e]  = sc;
            sfc_s[e] = sc + gate_b[e];            // choice-correction bias
        }
    }
    __syncthreads();

    if (tid == 0) {
        // group scores: sum of top-2 biased scores within each group of 4
        float gs[8];
        for (int g = 0; g < 8; ++g) {
            float m1 = -1e30f, m2 = -1e30f;
            for (int j = 0; j < 4; ++j) {
                float v = sfc_s[g * 4 + j];
                if (v > m1) { m2 = m1; m1 = v; } else if (v > m2) { m2 = v; }
            }
            gs[g] = m1 + m2;
        }
        // top-4 groups (strict > keeps lowest index on ties, matches lax.top_k)
        bool gsel[8] = {false,false,false,false,false,false,false,false};
        for (int k = 0; k < 4; ++k) {
            float best = -1e30f; int bi = 0;
            for (int g = 0; g < 8; ++g)
                if (!gsel[g] && gs[g] > best) { best = gs[g]; bi = g; }
            gsel[bi] = true;
        }
        // top-4 experts of where(group selected, sfc, 0.0)
        bool taken[NE];
        for (int e = 0; e < NE; ++e) taken[e] = false;
        int ids[4]; float tw[4]; float tsum = 0.f;
        for (int k = 0; k < 4; ++k) {
            float best = -1e30f; int bi = 0;
            for (int e = 0; e < NE; ++e) {
                if (taken[e]) continue;
                float v = gsel[e >> 2] ? sfc_s[e] : 0.0f;
                if (v > best) { best = v; bi = e; }
            }
            taken[bi] = true; ids[k] = bi;
            tw[k] = sc_s[bi];   // weights from UNbiased scores
            tsum += tw[k];
        }
        const float inv = 2.5f / tsum;  // fold ROUTED_SCALING into weight
        for (int k = 0; k < 4; ++k) {
            const int e = ids[k];
            const int pos = atomicAdd(&counts[e], 1);
            toks[e * T_TOK + pos] = t;
            wts[e * T_TOK + pos] = tw[k] * inv;
        }
    }
}

__global__ void scan_kernel(const int* __restrict__ counts, int* __restrict__ offs)
{
    if (threadIdx.x == 0) {
        int s = 0;
        for (int e = 0; e < NE; ++e) { offs[e] = s; s += counts[e]; }
    }
}

// ---------------- up-projection (+SiLU*up) ----------------
// C1 = Xg @ W1, C2 = Xg @ W2, act = silu(C1)*C2
// tiles: 64 rows x 64 cols, BK=16, 256 threads, each thread 4x4 per matrix
__global__ __launch_bounds__(256) void up_gemm(
    const float* __restrict__ x,
    const float* __restrict__ w1,   // [e][D][I] (or [D][I] when shared)
    const float* __restrict__ w2,
    const int*   __restrict__ counts,
    const int*   __restrict__ offs,
    const int*   __restrict__ toks,
    float*       __restrict__ act,
    int I, int is_shared)
{
    const int e = blockIdx.z;
    const int n_rows = is_shared ? T_TOK : counts[e];
    const int rt = blockIdx.y;
    if (rt * 64 >= n_rows) return;
    const int ct  = blockIdx.x;
    const int tid = threadIdx.x;
    const int tx = tid & 15, ty = tid >> 4;

    __shared__ float Xs[16][64];
    __shared__ float W1s[16][64];
    __shared__ float W2s[16][64];

    // X load mapping: row lm, k-quad lk
    const int lm = tid & 63;
    const int lk = (tid >> 6) * 4;
    int ltok = -1;
    if (rt * 64 + lm < n_rows)
        ltok = is_shared ? (rt * 64 + lm) : toks[e * T_TOK + rt * 64 + lm];

    // W load mapping: k row wk, 4 consecutive cols wn
    const int wk = tid >> 4;
    const int wn = (tid & 15) * 4;
    const size_t ebase = (size_t)(is_shared ? 0 : e) * DIM * (size_t)I;
    const float* w1b = w1 + ebase + (size_t)ct * 64 + wn;
    const float* w2b = w2 + ebase + (size_t)ct * 64 + wn;

    float acc1[4][4] = {{0}}, acc2[4][4] = {{0}};

    for (int k0 = 0; k0 < DIM; k0 += 16) {
        float4 xv = make_float4(0.f, 0.f, 0.f, 0.f);
        if (ltok >= 0) xv = *(const float4*)&x[(size_t)ltok * DIM + k0 + lk];
        Xs[lk + 0][lm] = xv.x; Xs[lk + 1][lm] = xv.y;
        Xs[lk + 2][lm] = xv.z; Xs[lk + 3][lm] = xv.w;

        float4 w1v = *(const float4*)&w1b[(size_t)(k0 + wk) * I];
        float4 w2v = *(const float4*)&w2b[(size_t)(k0 + wk) * I];
        *(float4*)&W1s[wk][wn] = w1v;
        *(float4*)&W2s[wk][wn] = w2v;
        __syncthreads();

        #pragma unroll
        for (int k = 0; k < 16; ++k) {
            float4 a4  = *(const float4*)&Xs[k][ty * 4];
            float4 b14 = *(const float4*)&W1s[k][tx * 4];
            float4 b24 = *(const float4*)&W2s[k][tx * 4];
            const float av[4]  = {a4.x, a4.y, a4.z, a4.w};
            const float b1v[4] = {b14.x, b14.y, b14.z, b14.w};
            const float b2v[4] = {b24.x, b24.y, b24.z, b24.w};
            #pragma unroll
            for (int i = 0; i < 4; ++i)
                #pragma unroll
                for (int j = 0; j < 4; ++j) {
                    acc1[i][j] += av[i] * b1v[j];
                    acc2[i][j] += av[i] * b2v[j];
                }
        }
        __syncthreads();
    }

    const int obase = is_shared ? 0 : offs[e];
    #pragma unroll
    for (int i = 0; i < 4; ++i) {
        const int slot = rt * 64 + ty * 4 + i;
        if (slot >= n_rows) continue;
        float* op = act + (size_t)(obase + slot) * I + ct * 64 + tx * 4;
        #pragma unroll
        for (int j = 0; j < 4; ++j) {
            const float g = acc1[i][j];
            const float u = acc2[i][j];
            op[j] = (g / (1.f + expf(-g))) * u;   // silu(g)*u
        }
    }
}

// ---------------- down-projection ----------------
// shared: out[t] = act[t] @ wd           (plain store)
// routed: out[t] += w_t * (act_row @ wd) (atomicAdd)
__global__ __launch_bounds__(256) void down_gemm(
    const float* __restrict__ act,
    const float* __restrict__ wd,   // [e][I][D] (or [I][D] when shared)
    float*       __restrict__ out,
    const int*   __restrict__ counts,
    const int*   __restrict__ offs,
    const int*   __restrict__ toks,
    const float* __restrict__ wts,
    int I, int is_shared)
{
    const int e = blockIdx.z;
    const int n_rows = is_shared ? T_TOK : counts[e];
    const int rt = blockIdx.y;
    if (rt * 64 >= n_rows) return;
    const int ct  = blockIdx.x;   // over D/64 = 32
    const int tid = threadIdx.x;
    const int tx = tid & 15, ty = tid >> 4;

    __shared__ float As[16][64];
    __shared__ float Ws[16][64];

    const int lm = tid & 63;
    const int lk = (tid >> 6) * 4;
    const int rbase = is_shared ? 0 : offs[e];
    const bool arow_ok = (rt * 64 + lm < n_rows);

    const int wk = tid >> 4;
    const int wn = (tid & 15) * 4;
    const float* wdb = wd + (size_t)(is_shared ? 0 : e) * I * DIM
                          + (size_t)ct * 64 + wn;

    float acc[4][4] = {{0}};

    for (int k0 = 0; k0 < I; k0 += 16) {
        float4 av = make_float4(0.f, 0.f, 0.f, 0.f);
        if (arow_ok)
            av = *(const float4*)&act[(size_t)(rbase + rt * 64 + lm) * I + k0 + lk];
        As[lk + 0][lm] = av.x; As[lk + 1][lm] = av.y;
        As[lk + 2][lm] = av.z; As[lk + 3][lm] = av.w;

        float4 wv = *(const float4*)&wdb[(size_t)(k0 + wk) * DIM];
        *(float4*)&Ws[wk][wn] = wv;
        __syncthreads();

        #pragma unroll
        for (int k = 0; k < 16; ++k) {
            float4 a4 = *(const float4*)&As[k][ty * 4];
            float4 b4 = *(const float4*)&Ws[k][tx * 4];
            const float avv[4] = {a4.x, a4.y, a4.z, a4.w};
            const float bvv[4] = {b4.x, b4.y, b4.z, b4.w};
            #pragma unroll
            for (int i = 0; i < 4; ++i)
                #pragma unroll
                for (int j = 0; j < 4; ++j)
                    acc[i][j] += avv[i] * bvv[j];
        }
        __syncthreads();
    }

    #pragma unroll
    for (int i = 0; i < 4; ++i) {
        const int slot = rt * 64 + ty * 4 + i;
        if (slot >= n_rows) continue;
        if (is_shared) {
            float* op = out + (size_t)slot * DIM + ct * 64 + tx * 4;
            #pragma unroll
            for (int j = 0; j < 4; ++j) op[j] = acc[i][j];
        } else {
            const int t = toks[e * T_TOK + slot];
            const float w = wts[e * T_TOK + slot];
            float* op = out + (size_t)t * DIM + ct * 64 + tx * 4;
            #pragma unroll
            for (int j = 0; j < 4; ++j) atomicAdd(&op[j], w * acc[i][j]);
        }
    }
}

// ---------------- launch ----------------
extern "C" void kernel_launch(void* const* d_in, const int* in_sizes, int n_in,
                              void* d_out, int out_size, void* d_ws, size_t ws_size,
                              hipStream_t stream)
{
    const float* x       = (const float*)d_in[0];
    const float* gate_w  = (const float*)d_in[1];
    const float* gate_b  = (const float*)d_in[2];
    const float* w_gate  = (const float*)d_in[3];
    const float* w_up    = (const float*)d_in[4];
    const float* w_down  = (const float*)d_in[5];
    const float* sw_gate = (const float*)d_in[6];
    const float* sw_up   = (const float*)d_in[7];
    const float* sw_down = (const float*)d_in[8];
    float* out = (float*)d_out;

    char* ws = (char*)d_ws;
    int*   counts = (int*)ws;                          // 128 B
    int*   offs   = (int*)(ws + 128);                  // 128 B
    int*   toks   = (int*)(ws + 256);                  // 32*1024*4 = 128 KB
    float* wts    = (float*)(ws + 256 + 131072);       // 128 KB
    float* act_r  = (float*)(ws + 262400);             // 4096*1408*4 = 23,068,672 B
    float* act_s  = (float*)(ws + 262400 + 23068672);  // 1024*2816*4 = 11,534,336 B

    hipMemsetAsync(counts, 0, 128, stream);
    gate_kernel<<<dim3(T_TOK), dim3(256), 0, stream>>>(x, gate_w, gate_b,
                                                       counts, toks, wts);
    scan_kernel<<<dim3(1), dim3(64), 0, stream>>>(counts, offs);

    // routed up: I_R/64 = 22 col tiles, up to 16 row tiles, 32 experts
    up_gemm<<<dim3(22, 16, 32), dim3(256), 0, stream>>>(
        x, w_gate, w_up, counts, offs, toks, act_r, I_R, 0);
    // shared up: I_S/64 = 44 col tiles, 16 row tiles
    up_gemm<<<dim3(44, 16, 1), dim3(256), 0, stream>>>(
        x, sw_gate, sw_up, counts, offs, toks, act_s, I_S, 1);

    // shared down FIRST (plain store), then routed down (atomicAdd)
    down_gemm<<<dim3(32, 16, 1), dim3(256), 0, stream>>>(
        act_s, sw_down, out, counts, offs, toks, wts, I_S, 1);
    down_gemm<<<dim3(32, 16, 32), dim3(256), 0, stream>>>(
        act_r, w_down, out, counts, offs, toks, wts, I_R, 0);
}

// Round 2
// 1802.792 us; speedup vs baseline: 1.4690x; 1.4690x over previous
//
#include <hip/hip_runtime.h>
#include <hip/hip_bf16.h>
#include <math.h>

#define T_TOK 1024
#define DIM   2048
#define NE    32
#define I_R   1408
#define I_S   2816
#define KPW   20   // u32 words per LDS row (= 40 bf16, padded from 32)

typedef short bf16x8 __attribute__((ext_vector_type(8)));
typedef float f32x4  __attribute__((ext_vector_type(4)));

static __device__ __forceinline__ unsigned short f2bf(float f) {
    __hip_bfloat16 h = __float2bfloat16(f);
    return __builtin_bit_cast(unsigned short, h);
}
static __device__ __forceinline__ unsigned int packbf(float lo, float hi) {
    return (unsigned int)f2bf(lo) | ((unsigned int)f2bf(hi) << 16);
}

// ---------------- gating ----------------
__global__ void gate_kernel(const float* __restrict__ x,
                            const float* __restrict__ gate_w,
                            const float* __restrict__ gate_b,
                            int* __restrict__ counts,
                            int* __restrict__ toks,
                            float* __restrict__ wts)
{
    const int t   = blockIdx.x;
    const int tid = threadIdx.x;
    __shared__ float xs[DIM];
    __shared__ float sc_s[NE];
    __shared__ float sfc_s[NE];

    for (int i = tid; i < DIM; i += 256) xs[i] = x[(size_t)t * DIM + i];
    __syncthreads();

    const int wave = tid >> 6, lane = tid & 63;
    for (int q = 0; q < 8; ++q) {
        const int e = wave * 8 + q;
        const float* gw = gate_w + (size_t)e * DIM;
        float s = 0.f;
        for (int d = lane; d < DIM; d += 64) s += xs[d] * gw[d];
        for (int off = 32; off >= 1; off >>= 1) s += __shfl_down(s, off, 64);
        if (lane == 0) {
            float logit = s + gate_b[e];
            float sc = 1.f / (1.f + expf(-logit));
            sc_s[e]  = sc;
            sfc_s[e] = sc + gate_b[e];
        }
    }
    __syncthreads();

    if (tid == 0) {
        float gs[8];
        for (int g = 0; g < 8; ++g) {
            float m1 = -1e30f, m2 = -1e30f;
            for (int j = 0; j < 4; ++j) {
                float v = sfc_s[g * 4 + j];
                if (v > m1) { m2 = m1; m1 = v; } else if (v > m2) { m2 = v; }
            }
            gs[g] = m1 + m2;
        }
        bool gsel[8] = {false,false,false,false,false,false,false,false};
        for (int k = 0; k < 4; ++k) {
            float best = -1e30f; int bi = 0;
            for (int g = 0; g < 8; ++g)
                if (!gsel[g] && gs[g] > best) { best = gs[g]; bi = g; }
            gsel[bi] = true;
        }
        bool taken[NE];
        for (int e = 0; e < NE; ++e) taken[e] = false;
        int ids[4]; float tw[4]; float tsum = 0.f;
        for (int k = 0; k < 4; ++k) {
            float best = -1e30f; int bi = 0;
            for (int e = 0; e < NE; ++e) {
                if (taken[e]) continue;
                float v = gsel[e >> 2] ? sfc_s[e] : 0.0f;
                if (v > best) { best = v; bi = e; }
            }
            taken[bi] = true; ids[k] = bi;
            tw[k] = sc_s[bi];
            tsum += tw[k];
        }
        const float inv = 2.5f / tsum;
        for (int k = 0; k < 4; ++k) {
            const int e = ids[k];
            const int pos = atomicAdd(&counts[e], 1);
            toks[e * T_TOK + pos] = t;
            wts[e * T_TOK + pos] = tw[k] * inv;
        }
    }
}

__global__ void scan_kernel(const int* __restrict__ counts, int* __restrict__ offs)
{
    if (threadIdx.x == 0) {
        int s = 0;
        for (int e = 0; e < NE; ++e) { offs[e] = s; s += counts[e]; }
    }
}

// ---------------- fused up-projection: act = silu(X@W1) * (X@W2), bf16 out ---
// block tile 192m x 64n, BK=32, 4 waves of 48m x 64n (3x4 mfma tiles, x2 mats)
__global__ __launch_bounds__(256) void up_mfma(
    const float* __restrict__ x,
    const float* __restrict__ w1,     // [e][D][I] fp32
    const float* __restrict__ w2,
    const int*   __restrict__ counts,
    const int*   __restrict__ offs,
    const int*   __restrict__ toks,
    unsigned short* __restrict__ act, // bf16 [rows][I]
    int I, int is_shared)
{
    const int e = blockIdx.z;
    const int n_rows = is_shared ? T_TOK : counts[e];
    const int mbase = blockIdx.y * 192;
    if (mbase >= n_rows) return;
    const int n0  = blockIdx.x * 64;
    const int tid = threadIdx.x;
    const int lane = tid & 63;
    const int w  = tid >> 6;
    const int lm = lane & 15;
    const int lg = lane >> 4;
    const int wm = w * 48;

    __shared__ unsigned int sm[(192 + 64 + 64) * KPW];
    unsigned int* As  = sm;
    unsigned int* B1s = sm + 192 * KPW;
    unsigned int* B2s = B1s + 64 * KPW;

    // A staging map: 32 rows/pass, 8 threads per row (4 floats each), 6 passes
    const int ar  = tid >> 3;
    const int akf = (tid & 7) * 4;
    int rtok[6];
    #pragma unroll
    for (int p = 0; p < 6; ++p) {
        const int m = mbase + ar + 32 * p;
        rtok[p] = (m < n_rows) ? (is_shared ? m : toks[e * T_TOK + m]) : -1;
    }

    // B staging map
    const int bn  = tid & 31;
    const int bkp = tid >> 5;  // 0..7 (k pair)
    const size_t ebase = (size_t)(is_shared ? 0 : e) * DIM * (size_t)I;
    const float* w1b = w1 + ebase + n0;
    const float* w2b = w2 + ebase + n0;

    f32x4 acc1[3][4], acc2[3][4];
    #pragma unroll
    for (int i = 0; i < 3; ++i)
        #pragma unroll
        for (int j = 0; j < 4; ++j) {
            acc1[i][j] = (f32x4){0.f, 0.f, 0.f, 0.f};
            acc2[i][j] = (f32x4){0.f, 0.f, 0.f, 0.f};
        }

    for (int k0 = 0; k0 < DIM; k0 += 32) {
        // ---- stage A (fp32 -> bf16, [m][k]) ----
        #pragma unroll
        for (int p = 0; p < 6; ++p) {
            float4 v = make_float4(0.f, 0.f, 0.f, 0.f);
            if (rtok[p] >= 0)
                v = *(const float4*)&x[(size_t)rtok[p] * DIM + k0 + akf];
            unsigned int* dst = &As[(ar + 32 * p) * KPW + (akf >> 1)];
            dst[0] = packbf(v.x, v.y);
            dst[1] = packbf(v.z, v.w);
        }
        // ---- stage B (fp32 [k][n] -> bf16 [n][k]) ----
        #pragma unroll
        for (int p = 0; p < 2; ++p) {
            const int k = k0 + 2 * bkp + 16 * p;
            const float* r0a = w1b + (size_t)k * I;
            const float* r1a = r0a + I;
            const float* r0b = w2b + (size_t)k * I;
            const float* r1b = r0b + I;
            #pragma unroll
            for (int j = 0; j < 2; ++j) {
                const int n = bn + 32 * j;
                B1s[n * KPW + bkp + 8 * p] = packbf(r0a[n], r1a[n]);
                B2s[n * KPW + bkp + 8 * p] = packbf(r0b[n], r1b[n]);
            }
        }
        __syncthreads();

        bf16x8 af[3], b1f[4], b2f[4];
        #pragma unroll
        for (int i = 0; i < 3; ++i)
            af[i] = *(const bf16x8*)&As[(wm + 16 * i + lm) * KPW + lg * 4];
        #pragma unroll
        for (int j = 0; j < 4; ++j) {
            b1f[j] = *(const bf16x8*)&B1s[(16 * j + lm) * KPW + lg * 4];
            b2f[j] = *(const bf16x8*)&B2s[(16 * j + lm) * KPW + lg * 4];
        }
        #pragma unroll
        for (int i = 0; i < 3; ++i)
            #pragma unroll
            for (int j = 0; j < 4; ++j) {
                acc1[i][j] = __builtin_amdgcn_mfma_f32_16x16x32_bf16(af[i], b1f[j], acc1[i][j], 0, 0, 0);
                acc2[i][j] = __builtin_amdgcn_mfma_f32_16x16x32_bf16(af[i], b2f[j], acc2[i][j], 0, 0, 0);
            }
        __syncthreads();
    }

    // ---- epilogue: silu(c1)*c2 -> bf16 ----
    const int obase = is_shared ? 0 : offs[e];
    #pragma unroll
    for (int i = 0; i < 3; ++i) {
        const int mloc = wm + 16 * i + lg * 4;
        #pragma unroll
        for (int j = 0; j < 4; ++j) {
            const int col = n0 + 16 * j + lm;
            #pragma unroll
            for (int r = 0; r < 4; ++r) {
                const int m = mloc + r;
                if (mbase + m < n_rows) {
                    const float g = acc1[i][j][r];
                    const float u = acc2[i][j][r];
                    act[(size_t)(obase + mbase + m) * I + col] =
                        f2bf(g / (1.f + expf(-g)) * u);
                }
            }
        }
    }
}

// ---------------- down-projection: out = act @ Wd ----------------
__global__ __launch_bounds__(256) void down_mfma(
    const unsigned short* __restrict__ act,  // bf16 [rows][I]
    const float* __restrict__ wd,            // [e][I][D] fp32
    float*       __restrict__ out,
    const int*   __restrict__ counts,
    const int*   __restrict__ offs,
    const int*   __restrict__ toks,
    const float* __restrict__ wts,
    int I, int is_shared)
{
    const int e = blockIdx.z;
    const int n_rows = is_shared ? T_TOK : counts[e];
    const int mbase = blockIdx.y * 192;
    if (mbase >= n_rows) return;
    const int n0  = blockIdx.x * 64;
    const int tid = threadIdx.x;
    const int lane = tid & 63;
    const int w  = tid >> 6;
    const int lm = lane & 15;
    const int lg = lane >> 4;
    const int wm = w * 48;

    __shared__ unsigned int sm[(192 + 64) * KPW];
    unsigned int* As = sm;
    unsigned int* Bs = sm + 192 * KPW;

    const int ar  = tid >> 3;
    const int akf = (tid & 7) * 4;
    const int rbase = is_shared ? 0 : offs[e];

    const int bn  = tid & 31;
    const int bkp = tid >> 5;
    const float* wdb = wd + (size_t)(is_shared ? 0 : e) * I * (size_t)DIM + n0;

    f32x4 acc[3][4];
    #pragma unroll
    for (int i = 0; i < 3; ++i)
        #pragma unroll
        for (int j = 0; j < 4; ++j)
            acc[i][j] = (f32x4){0.f, 0.f, 0.f, 0.f};

    for (int k0 = 0; k0 < I; k0 += 32) {
        // ---- stage A (bf16 passthrough, [m][k]) ----
        #pragma unroll
        for (int p = 0; p < 6; ++p) {
            const int m = ar + 32 * p;
            uint2 v = make_uint2(0u, 0u);
            if (mbase + m < n_rows)
                v = *(const uint2*)(act + (size_t)(rbase + mbase + m) * I + k0 + akf);
            unsigned int* dst = &As[m * KPW + (akf >> 1)];
            dst[0] = v.x;
            dst[1] = v.y;
        }
        // ---- stage B (fp32 [k][n] -> bf16 [n][k]) ----
        #pragma unroll
        for (int p = 0; p < 2; ++p) {
            const int k = k0 + 2 * bkp + 16 * p;
            const float* r0 = wdb + (size_t)k * DIM;
            const float* r1 = r0 + DIM;
            #pragma unroll
            for (int j = 0; j < 2; ++j) {
                const int n = bn + 32 * j;
                Bs[n * KPW + bkp + 8 * p] = packbf(r0[n], r1[n]);
            }
        }
        __syncthreads();

        bf16x8 af[3], bf[4];
        #pragma unroll
        for (int i = 0; i < 3; ++i)
            af[i] = *(const bf16x8*)&As[(wm + 16 * i + lm) * KPW + lg * 4];
        #pragma unroll
        for (int j = 0; j < 4; ++j)
            bf[j] = *(const bf16x8*)&Bs[(16 * j + lm) * KPW + lg * 4];
        #pragma unroll
        for (int i = 0; i < 3; ++i)
            #pragma unroll
            for (int j = 0; j < 4; ++j)
                acc[i][j] = __builtin_amdgcn_mfma_f32_16x16x32_bf16(af[i], bf[j], acc[i][j], 0, 0, 0);
        __syncthreads();
    }

    #pragma unroll
    for (int i = 0; i < 3; ++i) {
        const int mloc = wm + 16 * i + lg * 4;
        #pragma unroll
        for (int j = 0; j < 4; ++j) {
            const int col = n0 + 16 * j + lm;
            #pragma unroll
            for (int r = 0; r < 4; ++r) {
                const int slot = mbase + mloc + r;
                if (slot < n_rows) {
                    if (is_shared) {
                        out[(size_t)slot * DIM + col] = acc[i][j][r];
                    } else {
                        const int   t  = toks[e * T_TOK + slot];
                        const float wt = wts[e * T_TOK + slot];
                        atomicAdd(&out[(size_t)t * DIM + col], wt * acc[i][j][r]);
                    }
                }
            }
        }
    }
}

// ---------------- launch ----------------
extern "C" void kernel_launch(void* const* d_in, const int* in_sizes, int n_in,
                              void* d_out, int out_size, void* d_ws, size_t ws_size,
                              hipStream_t stream)
{
    const float* x       = (const float*)d_in[0];
    const float* gate_w  = (const float*)d_in[1];
    const float* gate_b  = (const float*)d_in[2];
    const float* w_gate  = (const float*)d_in[3];
    const float* w_up    = (const float*)d_in[4];
    const float* w_down  = (const float*)d_in[5];
    const float* sw_gate = (const float*)d_in[6];
    const float* sw_up   = (const float*)d_in[7];
    const float* sw_down = (const float*)d_in[8];
    float* out = (float*)d_out;

    char* ws = (char*)d_ws;
    int*   counts = (int*)ws;                               // 128 B
    int*   offs   = (int*)(ws + 128);                       // 128 B
    int*   toks   = (int*)(ws + 256);                       // 128 KB
    float* wts    = (float*)(ws + 256 + 131072);            // 128 KB
    unsigned short* act_r = (unsigned short*)(ws + 262400);             // 4096*1408*2
    unsigned short* act_s = (unsigned short*)(ws + 262400 + 11534336);  // 1024*2816*2

    hipMemsetAsync(counts, 0, 128, stream);
    gate_kernel<<<dim3(T_TOK), dim3(256), 0, stream>>>(x, gate_w, gate_b,
                                                       counts, toks, wts);
    scan_kernel<<<dim3(1), dim3(64), 0, stream>>>(counts, offs);

    // routed up: 22 col tiles x 6 row tiles x 32 experts (rt>0 mostly exit)
    up_mfma<<<dim3(I_R / 64, 6, NE), dim3(256), 0, stream>>>(
        x, w_gate, w_up, counts, offs, toks, act_r, I_R, 0);
    // shared up: 44 col tiles x 6 row tiles
    up_mfma<<<dim3(I_S / 64, 6, 1), dim3(256), 0, stream>>>(
        x, sw_gate, sw_up, counts, offs, toks, act_s, I_S, 1);

    // shared down FIRST (plain store), then routed down (atomicAdd)
    down_mfma<<<dim3(DIM / 64, 6, 1), dim3(256), 0, stream>>>(
        act_s, sw_down, out, counts, offs, toks, wts, I_S, 1);
    down_mfma<<<dim3(DIM / 64, 6, NE), dim3(256), 0, stream>>>(
        act_r, w_down, out, counts, offs, toks, wts, I_R, 0);
}